// Round 8
// baseline (520.223 us; speedup 1.0000x reference)
//
#include <hip/hip_runtime.h>
#include <hip/hip_bf16.h>
#include <hip/hip_fp16.h>

// GCN 3-layer, atomic-free hot path, fp16 storage / fp32 compute, MFMA GEMMs.
// Feature buffers ROW-MAJOR [N][C] fp16 (256B rows): gather phase-1 stages whole
// rows (16B/lane, 4-lane 64B segments -> 4x less line divergence than 32B plane
// rows), csr_row read once per layer. Phase-2: thread=(node, 8ch-group) owns its
// channels: one ds_read_b128 per edge, 8 fp32 acc chains, NO cross-thread
// reduction. CH=96 edges/chunk -> 26KB LDS -> 6 blocks/CU (75% occ).

#define K_DIM 128
#define SCAN_CHUNK 1024

typedef _Float16 f16x8 __attribute__((ext_vector_type(8)));
typedef float f32x4 __attribute__((ext_vector_type(4)));

static inline long long cdiv_ll(long long a, long long b) { return (a + b - 1) / b; }

// ---------------- CSR build ----------------
__global__ __launch_bounds__(256) void count_kernel(const int* __restrict__ col, int* __restrict__ cnt,
                                                    int* __restrict__ rank, int E) {
    int e = blockIdx.x * 256 + threadIdx.x;
    if (e < E) rank[e] = atomicAdd(&cnt[col[e]], 1);
}

__global__ __launch_bounds__(256) void dinv_kernel(const int* __restrict__ cnt, float* __restrict__ dinv, int N) {
    int n = blockIdx.x * 256 + threadIdx.x;
    if (n < N) {
        int d = cnt[n];
        dinv[n] = (d > 0) ? (1.0f / sqrtf((float)d)) : 0.0f;
    }
}

__global__ __launch_bounds__(256) void scan1_kernel(const int* __restrict__ cnt, int* __restrict__ off,
                                                    int* __restrict__ bsum, int N) {
    __shared__ int lds[256];
    const int t = threadIdx.x;
    const int base = blockIdx.x * SCAN_CHUNK;
    int v[4], s = 0;
#pragma unroll
    for (int j = 0; j < 4; ++j) {
        int i = base + t * 4 + j;
        v[j] = (i < N) ? cnt[i] : 0;
        s += v[j];
    }
    lds[t] = s;
    __syncthreads();
    for (int d = 1; d < 256; d <<= 1) {
        int x = (t >= d) ? lds[t - d] : 0;
        __syncthreads();
        lds[t] += x;
        __syncthreads();
    }
    int excl = lds[t] - s;
    if (t == 255) bsum[blockIdx.x] = lds[255];
    int run = excl;
#pragma unroll
    for (int j = 0; j < 4; ++j) {
        int i = base + t * 4 + j;
        if (i < N) off[i] = run;
        run += v[j];
    }
}

__global__ __launch_bounds__(256) void scan2_kernel(int* __restrict__ bsum, int G, int* __restrict__ off,
                                                    int N, int E) {
    __shared__ int lds[256];
    const int t = threadIdx.x;
    int s = (t < G) ? bsum[t] : 0;
    lds[t] = s;
    __syncthreads();
    for (int d = 1; d < 256; d <<= 1) {
        int x = (t >= d) ? lds[t - d] : 0;
        __syncthreads();
        lds[t] += x;
        __syncthreads();
    }
    if (t < G) bsum[t] = lds[t] - s;
    if (t == 0) off[N] = E;
}

__global__ __launch_bounds__(256) void scan3_kernel(int* __restrict__ off, const int* __restrict__ bsum, int N) {
    int add = bsum[blockIdx.x];
    const int base = blockIdx.x * SCAN_CHUNK;
#pragma unroll
    for (int j = 0; j < 4; ++j) {
        int i = base + threadIdx.x * 4 + j;
        if (i < N) off[i] += add;
    }
}

__global__ __launch_bounds__(256) void fill_kernel(const int* __restrict__ row, const int* __restrict__ col,
                                                   const int* __restrict__ off, const int* __restrict__ rank,
                                                   int* __restrict__ csr_row, int E) {
    int e = blockIdx.x * 256 + threadIdx.x;
    if (e < E) {
        int idx = off[col[e]] + rank[e];
        __builtin_nontemporal_store(row[e], &csr_row[idx]);
    }
}

// ---------------- W pack: fp32 [K][COUT] -> fp16 MFMA B-fragment order ----------------
template <int COUT>
__global__ __launch_bounds__(256) void pack_w_kernel(const float* __restrict__ W, _Float16* __restrict__ Wp) {
    constexpr int NT = COUT / 16;
    int t = blockIdx.x * 256 + threadIdx.x;
    if (t >= 4 * NT * 64) return;
    int lane = t & 63;
    int nt = (t >> 6) % NT;
    int kt = t / (64 * NT);
    int c = lane & 15, q = lane >> 4;
    f16x8 v;
#pragma unroll
    for (int j = 0; j < 8; ++j) {
        int k = kt * 32 + q * 8 + j;
        v[j] = (_Float16)W[k * COUT + nt * 16 + c];
    }
    *(f16x8*)&Wp[(size_t)t * 8] = v;
}

// ---------------- MFMA GEMM: g = dinv[n]*(A[n]@W); A fp32 or fp16 row-major;
// ---------------- output fp16 row-major [M][COUT] ----------------
template <int COUT, bool AF16>
__global__ __launch_bounds__(256) void gemm_mfma(const void* __restrict__ Av, const _Float16* __restrict__ Wp,
                                                 const float* __restrict__ dinv, _Float16* __restrict__ Cmat, int M) {
    constexpr int NT = COUT / 16;
    constexpr int NFRAG = 4 * NT * 64;
    __shared__ _Float16 Wlds[NFRAG * 8];

    const int t = threadIdx.x;
    for (int i = t; i < NFRAG; i += 256)
        *(f16x8*)&Wlds[(size_t)i * 8] = *(const f16x8*)&Wp[(size_t)i * 8];
    __syncthreads();

    const int lane = t & 63;
    const int wave = t >> 6;
    const int c = lane & 15;
    const int q = lane >> 4;
    const int row_base = blockIdx.x * 128 + wave * 32;

    f32x4 acc[2][NT];
#pragma unroll
    for (int rt = 0; rt < 2; ++rt)
#pragma unroll
        for (int nt = 0; nt < NT; ++nt) {
            acc[rt][nt][0] = 0.f; acc[rt][nt][1] = 0.f;
            acc[rt][nt][2] = 0.f; acc[rt][nt][3] = 0.f;
        }

#pragma unroll
    for (int kt = 0; kt < 4; ++kt) {
        f16x8 a[2];
#pragma unroll
        for (int rt = 0; rt < 2; ++rt) {
            int r = row_base + rt * 16 + c;
            r = (r < M) ? r : (M - 1);
            if (AF16) {
                a[rt] = *(const f16x8*)((const _Float16*)Av + (size_t)r * K_DIM + kt * 32 + q * 8);
            } else {
                const float* ap = (const float*)Av + (size_t)r * K_DIM + kt * 32 + q * 8;
                float4 v0 = *(const float4*)ap;
                float4 v1 = *(const float4*)(ap + 4);
                f16x8 av;
                av[0] = (_Float16)v0.x; av[1] = (_Float16)v0.y;
                av[2] = (_Float16)v0.z; av[3] = (_Float16)v0.w;
                av[4] = (_Float16)v1.x; av[5] = (_Float16)v1.y;
                av[6] = (_Float16)v1.z; av[7] = (_Float16)v1.w;
                a[rt] = av;
            }
        }
#pragma unroll
        for (int nt = 0; nt < NT; ++nt) {
            f16x8 b = *(const f16x8*)&Wlds[(size_t)((kt * NT + nt) * 64 + lane) * 8];
            acc[0][nt] = __builtin_amdgcn_mfma_f32_16x16x32_f16(a[0], b, acc[0][nt], 0, 0, 0);
            acc[1][nt] = __builtin_amdgcn_mfma_f32_16x16x32_f16(a[1], b, acc[1][nt], 0, 0, 0);
        }
    }

#pragma unroll
    for (int rt = 0; rt < 2; ++rt)
#pragma unroll
        for (int reg = 0; reg < 4; ++reg) {
            int row = row_base + rt * 16 + q * 4 + reg;
            if (row < M) {
                float dv = dinv[row];
#pragma unroll
                for (int nt = 0; nt < NT; ++nt)
                    Cmat[(size_t)row * COUT + nt * 16 + c] = (_Float16)(acc[rt][nt][reg] * dv);
            }
        }
}

// ---------------- LDS-staged row-major gather ----------------
// C channels; SUBS = C/8 threads per node (8 ch each); NTILE = 256/SUBS nodes
// per block; CH=96 edges per chunk staged as whole rows (16B/lane, coalesced).
// Phase 2: one ds_read_b128 per edge per thread, 8 fp32 acc, no reduction.
template <int C, bool RELU, typename OutT>
__global__ __launch_bounds__(256) void gather_row(const _Float16* __restrict__ g, const int* __restrict__ off,
                                                  const int* __restrict__ csr_row, const float* __restrict__ dinv,
                                                  const float* __restrict__ bias, OutT* __restrict__ outp, int N) {
    constexpr int SUBS = C / 8;            // 16 (C=128) or 8 (C=64)
    constexpr int LOG_SUBS = (SUBS == 16) ? 4 : 3;
    constexpr int NTILE = 256 / SUBS;      // 16 or 32
    constexpr int CH = 96;                 // edges per chunk
    constexpr int RST = C + 8;             // halves per LDS row (pad 16B)
    __shared__ __align__(16) _Float16 feat[CH * RST];
    __shared__ int off_s[NTILE + 1];

    const int t = threadIdx.x;
    const int node0 = blockIdx.x * NTILE;

    if (t <= NTILE) {
        int idx = node0 + t;
        off_s[t] = off[idx < N ? idx : N];
    }
    __syncthreads();

    const int n_loc = t >> LOG_SUBS;
    const int sub = t & (SUBS - 1);
    const int node = node0 + n_loc;
    const bool valid = node < N;
    const int sn0 = off_s[n_loc];
    const int sn1 = off_s[n_loc + 1];
    const int s_begin = off_s[0];
    const int s_end = off_s[NTILE];

    float acc[8];
#pragma unroll
    for (int k = 0; k < 8; ++k) acc[k] = 0.f;

    for (int cs = s_begin; cs < s_end; cs += CH) {
        const int ce = (cs + CH < s_end) ? (cs + CH) : s_end;
        const int cnt = ce - cs;
        // phase 1: stage whole rows; unit u = (row_local, seg)
        const int units = cnt << LOG_SUBS;
        for (int u = t; u < units; u += 256) {
            int rloc = u >> LOG_SUBS;
            int seg = u & (SUBS - 1);
            int r = csr_row[cs + rloc];
            f16x8 v = *(const f16x8*)(g + (size_t)r * C + seg * 8);
            *(f16x8*)&feat[rloc * RST + seg * 8] = v;
        }
        __syncthreads();
        // phase 2: accumulate this node's edges from LDS
        const int lo_s = (sn0 > cs) ? sn0 : cs;
        const int hi_s = (sn1 < ce) ? sn1 : ce;
        const _Float16* fb = &feat[sub * 8];
        for (int s = lo_s; s < hi_s; ++s) {
            f16x8 v = *(const f16x8*)&fb[(s - cs) * RST];
#pragma unroll
            for (int k = 0; k < 8; ++k) acc[k] += (float)v[k];
        }
        __syncthreads();
    }

    if (valid) {
        const float dv = dinv[node];
        const float* bp = bias + sub * 8;
        float o[8];
#pragma unroll
        for (int k = 0; k < 8; ++k) {
            o[k] = acc[k] * dv + bp[k];
            if (RELU) o[k] = fmaxf(o[k], 0.f);
        }
        if constexpr (sizeof(OutT) == 2) {
            f16x8 ov;
#pragma unroll
            for (int k = 0; k < 8; ++k) ov[k] = (_Float16)o[k];
            *(f16x8*)((_Float16*)outp + (size_t)node * C + sub * 8) = ov;
        } else {
            float* op = (float*)outp + (size_t)node * C + sub * 8;
            *(float4*)op = make_float4(o[0], o[1], o[2], o[3]);
            *(float4*)(op + 4) = make_float4(o[4], o[5], o[6], o[7]);
        }
    }
}

extern "C" void kernel_launch(void* const* d_in, const int* in_sizes, int n_in,
                              void* d_out, int out_size, void* d_ws, size_t ws_size,
                              hipStream_t stream) {
    const float* x  = (const float*)d_in[0];
    const int*   ei = (const int*)d_in[1];
    const float* W1 = (const float*)d_in[2];
    const float* b1 = (const float*)d_in[3];
    const float* W2 = (const float*)d_in[4];
    const float* b2 = (const float*)d_in[5];
    const float* W3 = (const float*)d_in[6];
    const float* b3 = (const float*)d_in[7];

    const int N = in_sizes[0] / 128;   // 100000
    const int E = in_sizes[1] / 2;     // 1600000
    const int* row = ei;
    const int* col = ei + E;
    const int G = (int)cdiv_ll(N, SCAN_CHUNK);

    // workspace layout
    char* wsb = (char*)d_ws;
    int*      cnt     = (int*)wsb;      wsb += (size_t)N * 4;
    float*    dinv    = (float*)wsb;    wsb += (size_t)N * 4;
    int*      off     = (int*)wsb;      wsb += (size_t)(N + 1) * 4;
    int*      bsum    = (int*)wsb;      wsb += 256 * 4;
    int*      rank    = (int*)wsb;      wsb += (size_t)E * 4;
    int*      csr_row = (int*)wsb;      wsb += (size_t)E * 4;
    wsb = (char*)((((uintptr_t)wsb) + 15) & ~(uintptr_t)15);
    _Float16* Wp1     = (_Float16*)wsb; wsb += 16384 * 2;
    _Float16* Wp2     = (_Float16*)wsb; wsb += 16384 * 2;
    _Float16* Wp3     = (_Float16*)wsb; wsb += 8192 * 2;
    _Float16* bufA    = (_Float16*)wsb; wsb += (size_t)N * 128 * 2;   // row-major [N][128]
    _Float16* bufB    = (_Float16*)wsb;                               // row-major
    float*    out     = (float*)d_out;

    // ---- CSR build + dinv + W pack ----
    hipMemsetAsync(cnt, 0, (size_t)N * 4, stream);
    count_kernel<<<cdiv_ll(E, 256), 256, 0, stream>>>(col, cnt, rank, E);
    dinv_kernel<<<cdiv_ll(N, 256), 256, 0, stream>>>(cnt, dinv, N);
    scan1_kernel<<<G, 256, 0, stream>>>(cnt, off, bsum, N);
    scan2_kernel<<<1, 256, 0, stream>>>(bsum, G, off, N, E);
    scan3_kernel<<<G, 256, 0, stream>>>(off, bsum, N);
    fill_kernel<<<cdiv_ll(E, 256), 256, 0, stream>>>(row, col, off, rank, csr_row, E);
    pack_w_kernel<128><<<8, 256, 0, stream>>>(W1, Wp1);
    pack_w_kernel<128><<<8, 256, 0, stream>>>(W2, Wp2);
    pack_w_kernel<64><<<4, 256, 0, stream>>>(W3, Wp3);

    const long long gemmBlocks = cdiv_ll(N, 128);
    const long long g128Blocks = cdiv_ll(N, 16);   // NTILE=16 for C=128
    const long long g64Blocks  = cdiv_ll(N, 32);   // NTILE=32 for C=64

    // ---- layer 1 ----
    gemm_mfma<128, false><<<gemmBlocks, 256, 0, stream>>>(x, Wp1, dinv, bufA, N);
    gather_row<128, true, _Float16><<<g128Blocks, 256, 0, stream>>>(bufA, off, csr_row, dinv, b1, bufB, N);

    // ---- layer 2 ----
    gemm_mfma<128, true><<<gemmBlocks, 256, 0, stream>>>(bufB, Wp2, dinv, bufA, N);
    gather_row<128, true, _Float16><<<g128Blocks, 256, 0, stream>>>(bufA, off, csr_row, dinv, b2, bufB, N);

    // ---- layer 3 ----
    gemm_mfma<64, true><<<gemmBlocks, 256, 0, stream>>>(bufB, Wp3, dinv, bufA, N);
    gather_row<64, false, float><<<g64Blocks, 256, 0, stream>>>(bufA, off, csr_row, dinv, b3, out, N);
}

// Round 9
// 503.338 us; speedup vs baseline: 1.0335x; 1.0335x over previous
//
#include <hip/hip_runtime.h>
#include <hip/hip_bf16.h>
#include <hip/hip_fp16.h>

// GCN 3-layer, atomic-free hot path, fp16 storage / fp32 compute, MFMA GEMMs.
// Feature buffers ROW-MAJOR [N][C] fp16. Gather: block = NTILE nodes; per chunk
// of CH edges: stage chunk k+1's rows into REGISTERS (loads in flight) while
// accumulating chunk k from LDS, then commit regs->LDS. Single LDS buffer
// (12.3KB @ C=128) -> ~8 blocks/CU; pipelining + occupancy maximize outstanding
// L2 misses (the measured bottleneck). Segment-rotation swizzle spreads LDS banks.

#define K_DIM 128
#define SCAN_CHUNK 1024

typedef _Float16 f16x8 __attribute__((ext_vector_type(8)));
typedef float f32x4 __attribute__((ext_vector_type(4)));

static inline long long cdiv_ll(long long a, long long b) { return (a + b - 1) / b; }

// ---------------- CSR build ----------------
__global__ __launch_bounds__(256) void count_kernel(const int* __restrict__ col, int* __restrict__ cnt,
                                                    int* __restrict__ rank, int E) {
    int e = blockIdx.x * 256 + threadIdx.x;
    if (e < E) rank[e] = atomicAdd(&cnt[col[e]], 1);
}

// scan1 also produces dinv (fused old dinv_kernel)
__global__ __launch_bounds__(256) void scan1_kernel(const int* __restrict__ cnt, int* __restrict__ off,
                                                    int* __restrict__ bsum, float* __restrict__ dinv, int N) {
    __shared__ int lds[256];
    const int t = threadIdx.x;
    const int base = blockIdx.x * SCAN_CHUNK;
    int v[4], s = 0;
#pragma unroll
    for (int j = 0; j < 4; ++j) {
        int i = base + t * 4 + j;
        v[j] = (i < N) ? cnt[i] : 0;
        if (i < N) dinv[i] = (v[j] > 0) ? (1.0f / sqrtf((float)v[j])) : 0.0f;
        s += v[j];
    }
    lds[t] = s;
    __syncthreads();
    for (int d = 1; d < 256; d <<= 1) {
        int x = (t >= d) ? lds[t - d] : 0;
        __syncthreads();
        lds[t] += x;
        __syncthreads();
    }
    int excl = lds[t] - s;
    if (t == 255) bsum[blockIdx.x] = lds[255];
    int run = excl;
#pragma unroll
    for (int j = 0; j < 4; ++j) {
        int i = base + t * 4 + j;
        if (i < N) off[i] = run;
        run += v[j];
    }
}

__global__ __launch_bounds__(256) void scan2_kernel(int* __restrict__ bsum, int G, int* __restrict__ off,
                                                    int N, int E) {
    __shared__ int lds[256];
    const int t = threadIdx.x;
    int s = (t < G) ? bsum[t] : 0;
    lds[t] = s;
    __syncthreads();
    for (int d = 1; d < 256; d <<= 1) {
        int x = (t >= d) ? lds[t - d] : 0;
        __syncthreads();
        lds[t] += x;
        __syncthreads();
    }
    if (t < G) bsum[t] = lds[t] - s;
    if (t == 0) off[N] = E;
}

__global__ __launch_bounds__(256) void scan3_kernel(int* __restrict__ off, const int* __restrict__ bsum, int N) {
    int add = bsum[blockIdx.x];
    const int base = blockIdx.x * SCAN_CHUNK;
#pragma unroll
    for (int j = 0; j < 4; ++j) {
        int i = base + threadIdx.x * 4 + j;
        if (i < N) off[i] += add;
    }
}

__global__ __launch_bounds__(256) void fill_kernel(const int* __restrict__ row, const int* __restrict__ col,
                                                   const int* __restrict__ off, const int* __restrict__ rank,
                                                   int* __restrict__ csr_row, int E) {
    int e = blockIdx.x * 256 + threadIdx.x;
    if (e < E) {
        int idx = off[col[e]] + rank[e];
        __builtin_nontemporal_store(row[e], &csr_row[idx]);
    }
}

// ---------------- W pack: fp32 [K][COUT] -> fp16 MFMA B-fragment order (all 3 in one) ----------------
template <int COUT>
__device__ __forceinline__ void pack_body(const float* __restrict__ W, _Float16* __restrict__ Wp, int t) {
    constexpr int NT = COUT / 16;
    if (t >= 4 * NT * 64) return;
    int lane = t & 63;
    int nt = (t >> 6) % NT;
    int kt = t / (64 * NT);
    int c = lane & 15, q = lane >> 4;
    f16x8 v;
#pragma unroll
    for (int j = 0; j < 8; ++j) {
        int k = kt * 32 + q * 8 + j;
        v[j] = (_Float16)W[k * COUT + nt * 16 + c];
    }
    *(f16x8*)&Wp[(size_t)t * 8] = v;
}

__global__ __launch_bounds__(256) void pack_all_kernel(const float* __restrict__ W1, const float* __restrict__ W2,
                                                       const float* __restrict__ W3, _Float16* __restrict__ Wp1,
                                                       _Float16* __restrict__ Wp2, _Float16* __restrict__ Wp3) {
    int b = blockIdx.x;
    if (b < 8)       pack_body<128>(W1, Wp1, b * 256 + threadIdx.x);
    else if (b < 16) pack_body<128>(W2, Wp2, (b - 8) * 256 + threadIdx.x);
    else             pack_body<64>(W3, Wp3, (b - 16) * 256 + threadIdx.x);
}

// ---------------- MFMA GEMM: g = dinv[n]*(A[n]@W); A fp32 or fp16 row-major;
// ---------------- output fp16 row-major [M][COUT] ----------------
template <int COUT, bool AF16>
__global__ __launch_bounds__(256) void gemm_mfma(const void* __restrict__ Av, const _Float16* __restrict__ Wp,
                                                 const float* __restrict__ dinv, _Float16* __restrict__ Cmat, int M) {
    constexpr int NT = COUT / 16;
    constexpr int NFRAG = 4 * NT * 64;
    __shared__ _Float16 Wlds[NFRAG * 8];

    const int t = threadIdx.x;
    for (int i = t; i < NFRAG; i += 256)
        *(f16x8*)&Wlds[(size_t)i * 8] = *(const f16x8*)&Wp[(size_t)i * 8];
    __syncthreads();

    const int lane = t & 63;
    const int wave = t >> 6;
    const int c = lane & 15;
    const int q = lane >> 4;
    const int row_base = blockIdx.x * 128 + wave * 32;

    f32x4 acc[2][NT];
#pragma unroll
    for (int rt = 0; rt < 2; ++rt)
#pragma unroll
        for (int nt = 0; nt < NT; ++nt) {
            acc[rt][nt][0] = 0.f; acc[rt][nt][1] = 0.f;
            acc[rt][nt][2] = 0.f; acc[rt][nt][3] = 0.f;
        }

#pragma unroll
    for (int kt = 0; kt < 4; ++kt) {
        f16x8 a[2];
#pragma unroll
        for (int rt = 0; rt < 2; ++rt) {
            int r = row_base + rt * 16 + c;
            r = (r < M) ? r : (M - 1);
            if (AF16) {
                a[rt] = *(const f16x8*)((const _Float16*)Av + (size_t)r * K_DIM + kt * 32 + q * 8);
            } else {
                const float* ap = (const float*)Av + (size_t)r * K_DIM + kt * 32 + q * 8;
                float4 v0 = *(const float4*)ap;
                float4 v1 = *(const float4*)(ap + 4);
                f16x8 av;
                av[0] = (_Float16)v0.x; av[1] = (_Float16)v0.y;
                av[2] = (_Float16)v0.z; av[3] = (_Float16)v0.w;
                av[4] = (_Float16)v1.x; av[5] = (_Float16)v1.y;
                av[6] = (_Float16)v1.z; av[7] = (_Float16)v1.w;
                a[rt] = av;
            }
        }
#pragma unroll
        for (int nt = 0; nt < NT; ++nt) {
            f16x8 b = *(const f16x8*)&Wlds[(size_t)((kt * NT + nt) * 64 + lane) * 8];
            acc[0][nt] = __builtin_amdgcn_mfma_f32_16x16x32_f16(a[0], b, acc[0][nt], 0, 0, 0);
            acc[1][nt] = __builtin_amdgcn_mfma_f32_16x16x32_f16(a[1], b, acc[1][nt], 0, 0, 0);
        }
    }

#pragma unroll
    for (int rt = 0; rt < 2; ++rt)
#pragma unroll
        for (int reg = 0; reg < 4; ++reg) {
            int row = row_base + rt * 16 + q * 4 + reg;
            if (row < M) {
                float dv = dinv[row];
#pragma unroll
                for (int nt = 0; nt < NT; ++nt)
                    Cmat[(size_t)row * COUT + nt * 16 + c] = (_Float16)(acc[rt][nt][reg] * dv);
            }
        }
}

// ---------------- pipelined LDS gather ----------------
// thread = (node, sub): sub owns 8 channels. Per chunk: stage k+1 to registers
// (loads in flight), accumulate k from LDS, sync, commit regs->LDS, sync.
// LDS layout swizzled: row rloc stores channel-group sub at slot (sub+rloc)&mask.
template <int C, bool RELU, typename OutT>
__global__ __launch_bounds__(256) void gather_pipe(const _Float16* __restrict__ g, const int* __restrict__ off,
                                                   const int* __restrict__ csr_row, const float* __restrict__ dinv,
                                                   const float* __restrict__ bias, OutT* __restrict__ outp, int N) {
    constexpr int SUBS = C / 8;               // 16 (C=128) / 8 (C=64)
    constexpr int LS = (SUBS == 16) ? 4 : 3;
    constexpr int NTILE = 256 / SUBS;         // 16 / 32
    constexpr int CH = (C == 128) ? 48 : 64;  // edges per chunk
    constexpr int UPT = CH * SUBS / 256;      // 16B units per thread (3 / 2)
    __shared__ __align__(16) _Float16 feat[CH * C];
    __shared__ int off_s[NTILE + 1];

    const int t = threadIdx.x;
    const int node0 = blockIdx.x * NTILE;

    if (t <= NTILE) {
        int idx = node0 + t;
        off_s[t] = off[idx < N ? idx : N];
    }
    __syncthreads();

    const int n_loc = t >> LS;
    const int sub = t & (SUBS - 1);
    const int node = node0 + n_loc;
    const bool valid = node < N;
    const int sn0 = off_s[n_loc];
    const int sn1 = off_s[n_loc + 1];
    const int s_begin = off_s[0];
    const int s_end = off_s[NTILE];

    float acc[8];
#pragma unroll
    for (int k = 0; k < 8; ++k) acc[k] = 0.f;

    f16x8 stg[UPT];

    // --- stage: load chunk's rows into registers (swizzled source segment) ---
    auto stage = [&](int cs) {
        int ce = (cs + CH < s_end) ? (cs + CH) : s_end;
        int units = (ce - cs) << LS;
#pragma unroll
        for (int i = 0; i < UPT; ++i) {
            int u = t + i * 256;
            if (u < units) {
                int rloc = u >> LS;
                int slot = u & (SUBS - 1);
                int seg = (slot - rloc) & (SUBS - 1);
                int r = csr_row[cs + rloc];
                stg[i] = *(const f16x8*)(g + (size_t)r * C + seg * 8);
            }
        }
    };
    // --- commit: registers -> LDS ---
    auto commit = [&](int cs) {
        int ce = (cs + CH < s_end) ? (cs + CH) : s_end;
        int units = (ce - cs) << LS;
#pragma unroll
        for (int i = 0; i < UPT; ++i) {
            int u = t + i * 256;
            if (u < units) *(f16x8*)&feat[u * 8] = stg[i];
        }
    };

    if (s_begin < s_end) {
        stage(s_begin);
        commit(s_begin);
        __syncthreads();
        for (int cs = s_begin; cs < s_end; cs += CH) {
            const int nxt = cs + CH;
            const bool more = nxt < s_end;
            if (more) stage(nxt);                 // loads in flight during compute
            const int ce = more ? nxt : s_end;
            const int lo_s = (sn0 > cs) ? sn0 : cs;
            const int hi_s = (sn1 < ce) ? sn1 : ce;
            for (int s = lo_s; s < hi_s; ++s) {
                int rl = s - cs;
                int slot = (sub + rl) & (SUBS - 1);
                f16x8 v = *(const f16x8*)&feat[rl * C + slot * 8];
#pragma unroll
                for (int k = 0; k < 8; ++k) acc[k] += (float)v[k];
            }
            __syncthreads();
            if (more) {
                commit(nxt);
                __syncthreads();
            }
        }
    }

    if (valid) {
        const float dv = dinv[node];
        const float* bp = bias + sub * 8;
        float o[8];
#pragma unroll
        for (int k = 0; k < 8; ++k) {
            o[k] = acc[k] * dv + bp[k];
            if (RELU) o[k] = fmaxf(o[k], 0.f);
        }
        if constexpr (sizeof(OutT) == 2) {
            f16x8 ov;
#pragma unroll
            for (int k = 0; k < 8; ++k) ov[k] = (_Float16)o[k];
            *(f16x8*)((_Float16*)outp + (size_t)node * C + sub * 8) = ov;
        } else {
            float* op = (float*)outp + (size_t)node * C + sub * 8;
            *(float4*)op = make_float4(o[0], o[1], o[2], o[3]);
            *(float4*)(op + 4) = make_float4(o[4], o[5], o[6], o[7]);
        }
    }
}

extern "C" void kernel_launch(void* const* d_in, const int* in_sizes, int n_in,
                              void* d_out, int out_size, void* d_ws, size_t ws_size,
                              hipStream_t stream) {
    const float* x  = (const float*)d_in[0];
    const int*   ei = (const int*)d_in[1];
    const float* W1 = (const float*)d_in[2];
    const float* b1 = (const float*)d_in[3];
    const float* W2 = (const float*)d_in[4];
    const float* b2 = (const float*)d_in[5];
    const float* W3 = (const float*)d_in[6];
    const float* b3 = (const float*)d_in[7];

    const int N = in_sizes[0] / 128;   // 100000
    const int E = in_sizes[1] / 2;     // 1600000
    const int* row = ei;
    const int* col = ei + E;
    const int G = (int)cdiv_ll(N, SCAN_CHUNK);

    // workspace layout
    char* wsb = (char*)d_ws;
    int*      cnt     = (int*)wsb;      wsb += (size_t)N * 4;
    float*    dinv    = (float*)wsb;    wsb += (size_t)N * 4;
    int*      off     = (int*)wsb;      wsb += (size_t)(N + 1) * 4;
    int*      bsum    = (int*)wsb;      wsb += 256 * 4;
    int*      rank    = (int*)wsb;      wsb += (size_t)E * 4;
    int*      csr_row = (int*)wsb;      wsb += (size_t)E * 4;
    wsb = (char*)((((uintptr_t)wsb) + 15) & ~(uintptr_t)15);
    _Float16* Wp1     = (_Float16*)wsb; wsb += 16384 * 2;
    _Float16* Wp2     = (_Float16*)wsb; wsb += 16384 * 2;
    _Float16* Wp3     = (_Float16*)wsb; wsb += 8192 * 2;
    _Float16* bufA    = (_Float16*)wsb; wsb += (size_t)N * 128 * 2;   // row-major [N][128]
    _Float16* bufB    = (_Float16*)wsb;                               // row-major
    float*    out     = (float*)d_out;

    // ---- CSR build + dinv + W pack ----
    hipMemsetAsync(cnt, 0, (size_t)N * 4, stream);
    count_kernel<<<cdiv_ll(E, 256), 256, 0, stream>>>(col, cnt, rank, E);
    scan1_kernel<<<G, 256, 0, stream>>>(cnt, off, bsum, dinv, N);
    scan2_kernel<<<1, 256, 0, stream>>>(bsum, G, off, N, E);
    scan3_kernel<<<G, 256, 0, stream>>>(off, bsum, N);
    fill_kernel<<<cdiv_ll(E, 256), 256, 0, stream>>>(row, col, off, rank, csr_row, E);
    pack_all_kernel<<<20, 256, 0, stream>>>(W1, W2, W3, Wp1, Wp2, Wp3);

    const long long gemmBlocks = cdiv_ll(N, 128);
    const long long g128Blocks = cdiv_ll(N, 16);   // NTILE=16 for C=128
    const long long g64Blocks  = cdiv_ll(N, 32);   // NTILE=32 for C=64

    // ---- layer 1 ----
    gemm_mfma<128, false><<<gemmBlocks, 256, 0, stream>>>(x, Wp1, dinv, bufA, N);
    gather_pipe<128, true, _Float16><<<g128Blocks, 256, 0, stream>>>(bufA, off, csr_row, dinv, b1, bufB, N);

    // ---- layer 2 ----
    gemm_mfma<128, true><<<gemmBlocks, 256, 0, stream>>>(bufB, Wp2, dinv, bufA, N);
    gather_pipe<128, true, _Float16><<<g128Blocks, 256, 0, stream>>>(bufA, off, csr_row, dinv, b2, bufB, N);

    // ---- layer 3 ----
    gemm_mfma<64, true><<<gemmBlocks, 256, 0, stream>>>(bufB, Wp3, dinv, bufA, N);
    gather_pipe<64, false, float><<<g64Blocks, 256, 0, stream>>>(bufA, off, csr_row, dinv, b3, out, N);
}